// Round 1
// baseline (2906.150 us; speedup 1.0000x reference)
//
#include <hip/hip_runtime.h>
#include <stdint.h>

#define DM  1024
#define NB  8
#define LQ  4096
#define SSQ 4096
#define NH  16
#define HE  64
#define UU  40

using u16 = unsigned short;
using u32 = unsigned int;

__device__ __forceinline__ u16 f2bf(float x) {
  u32 u = __float_as_uint(x);
  u32 r = (u + 0x7fffu + ((u >> 16) & 1u)) >> 16;   // RNE
  return (u16)r;
}

// load 8 consecutive elements (fp32 or bf16 storage) into float[8]
template<bool KV16>
__device__ __forceinline__ void load8(const void* base, long off, float* f) {
  if (KV16) {
    uint4 raw = *(const uint4*)((const u16*)base + off);
    u32 w[4] = {raw.x, raw.y, raw.z, raw.w};
#pragma unroll
    for (int z = 0; z < 4; z++) {
      f[2*z]   = __uint_as_float(w[z] << 16);
      f[2*z+1] = __uint_as_float(w[z] & 0xffff0000u);
    }
  } else {
    const float* p = (const float*)base + off;
    float4 a = *(const float4*)p;
    float4 b = *(const float4*)(p + 4);
    f[0]=a.x; f[1]=a.y; f[2]=a.z; f[3]=a.w;
    f[4]=b.x; f[5]=b.y; f[6]=b.z; f[7]=b.w;
  }
}

// ---------------- GEMM: C[r,o] = sum_d X[r,d]*W[o,d] + bias[o], D = 1024 ----
// 128x128 tile, k-tile 16, 256 threads, 8x8 micro-tile.
template<bool GATHER, bool OUT_BF16>
__global__ __launch_bounds__(256, 2)
void gemm_xwt(const float* __restrict__ X, const float* __restrict__ W,
              const float* __restrict__ bias, void* __restrict__ outp,
              int R, const int* __restrict__ sidx)
{
  __shared__ float Xs[16][132];
  __shared__ float Ws[16][132];
  const int t  = threadIdx.x;
  const int r0 = blockIdx.x * 128;
  const int o0 = blockIdx.y * 128;
  const int tx = t & 15, ty = t >> 4;

  float acc[8][8];
#pragma unroll
  for (int i = 0; i < 8; i++)
#pragma unroll
    for (int jj = 0; jj < 8; jj++) acc[i][jj] = 0.f;

  // staging: rows t/4 (+64), cols (t%4)*4 .. +3 within the 16-wide k-tile
  const int row0 = t >> 2;
  const int c4   = (t & 3) * 4;
  long xsrc[2]; const float* wsrc[2];
#pragma unroll
  for (int p = 0; p < 2; p++) {
    int r = r0 + row0 + p*64;
    int rr = (r < R) ? r : (R - 1);
    long s;
    if (GATHER) { int bb = rr / UU, uu = rr - bb*UU; s = (long)(bb*LQ + sidx[uu]) * DM; }
    else        { s = (long)rr * DM; }
    xsrc[p] = s;
    wsrc[p] = W + (long)(o0 + row0 + p*64) * DM;
  }

  for (int k0 = 0; k0 < DM; k0 += 16) {
    float4 xv[2], wv[2];
#pragma unroll
    for (int p = 0; p < 2; p++) {
      xv[p] = *(const float4*)(X + xsrc[p] + k0 + c4);
      wv[p] = *(const float4*)(wsrc[p] + k0 + c4);
    }
    __syncthreads();
#pragma unroll
    for (int p = 0; p < 2; p++) {
      int rr = row0 + p*64;
      Xs[c4+0][rr] = xv[p].x; Xs[c4+1][rr] = xv[p].y;
      Xs[c4+2][rr] = xv[p].z; Xs[c4+3][rr] = xv[p].w;
      Ws[c4+0][rr] = wv[p].x; Ws[c4+1][rr] = wv[p].y;
      Ws[c4+2][rr] = wv[p].z; Ws[c4+3][rr] = wv[p].w;
    }
    __syncthreads();
#pragma unroll
    for (int kk = 0; kk < 16; kk++) {
      float4 a0 = *(const float4*)&Xs[kk][ty*8];
      float4 a1 = *(const float4*)&Xs[kk][ty*8+4];
      float4 b0 = *(const float4*)&Ws[kk][tx*8];
      float4 b1 = *(const float4*)&Ws[kk][tx*8+4];
      float xa[8] = {a0.x,a0.y,a0.z,a0.w,a1.x,a1.y,a1.z,a1.w};
      float wb[8] = {b0.x,b0.y,b0.z,b0.w,b1.x,b1.y,b1.z,b1.w};
#pragma unroll
      for (int i = 0; i < 8; i++)
#pragma unroll
        for (int jj = 0; jj < 8; jj++)
          acc[i][jj] = fmaf(xa[i], wb[jj], acc[i][jj]);
    }
  }

  const int orow = o0 + tx*8;
  float bb[8];
#pragma unroll
  for (int jj = 0; jj < 8; jj++) bb[jj] = bias[orow + jj];
#pragma unroll
  for (int i = 0; i < 8; i++) {
    int r = r0 + ty*8 + i;
    if (r < R) {
      if (OUT_BF16) {
        union { u16 h[8]; uint4 v; } pk;
#pragma unroll
        for (int jj = 0; jj < 8; jj++) pk.h[jj] = f2bf(acc[i][jj] + bb[jj]);
        *(uint4*)((u16*)outp + (long)r*DM + orow) = pk.v;
      } else {
        float* op = (float*)outp + (long)r*DM + orow;
        *(float4*)op       = make_float4(acc[i][0]+bb[0], acc[i][1]+bb[1],
                                         acc[i][2]+bb[2], acc[i][3]+bb[3]);
        *((float4*)op + 1) = make_float4(acc[i][4]+bb[4], acc[i][5]+bb[5],
                                         acc[i][6]+bb[6], acc[i][7]+bb[7]);
      }
    }
  }
}

// ---------------- scores + online softmax stats --------------------------
// block = (h, b); 256 threads: ig = t/32 -> u-group of 5, j = t%32 -> s lane.
// Writes raw scores into the attn output region; (m, l) per row to stats.
template<bool KV16>
__global__ __launch_bounds__(256, 2)
void attn_scores(const float* __restrict__ Qs, const void* __restrict__ Kkv,
                 float* __restrict__ attn, float* __restrict__ stats)
{
  const int h = blockIdx.x, b = blockIdx.y;
  __shared__ float Qss[UU][HE];
  __shared__ float Ks[64][68];
  const int t  = threadIdx.x;
  const int j  = t & 31, ig = t >> 5;

  for (int idx = t; idx < UU*HE; idx += 256) {
    int u = idx >> 6, e = idx & 63;
    Qss[u][e] = Qs[(long)(b*UU+u)*DM + h*HE + e];
  }
  float m[5], l[5];
#pragma unroll
  for (int q = 0; q < 5; q++) { m[q] = -1e30f; l[q] = 0.f; }

  for (int s0 = 0; s0 < SSQ; s0 += 64) {
    __syncthreads();
    for (int idx = t; idx < 512; idx += 256) {
      int sl = idx >> 3, c8 = (idx & 7) * 8;
      float f[8];
      load8<KV16>(Kkv, (long)(b*SSQ + s0 + sl)*DM + h*HE + c8, f);
#pragma unroll
      for (int z = 0; z < 8; z++) Ks[sl][c8+z] = f[z];
    }
    __syncthreads();

    float acc0[5] = {0,0,0,0,0}, acc1[5] = {0,0,0,0,0};
#pragma unroll
    for (int e4 = 0; e4 < 64; e4 += 4) {
      float4 k0 = *(const float4*)&Ks[j][e4];
      float4 k1 = *(const float4*)&Ks[j+32][e4];
#pragma unroll
      for (int q = 0; q < 5; q++) {
        float4 qv = *(const float4*)&Qss[ig*5+q][e4];
        acc0[q] += qv.x*k0.x + qv.y*k0.y + qv.z*k0.z + qv.w*k0.w;
        acc1[q] += qv.x*k1.x + qv.y*k1.y + qv.z*k1.z + qv.w*k1.w;
      }
    }
    const float scale = 0.03125f;  // 1024^-0.5
#pragma unroll
    for (int q = 0; q < 5; q++) {
      int u = ig*5 + q;
      long row = ((long)(b*NH + h)*UU + u) * SSQ;
      float x0 = acc0[q]*scale, x1 = acc1[q]*scale;
      attn[row + s0 + j]      = x0;
      attn[row + s0 + 32 + j] = x1;
      float mn = fmaxf(m[q], fmaxf(x0, x1));
      l[q] = l[q]*__expf(m[q]-mn) + __expf(x0-mn) + __expf(x1-mn);
      m[q] = mn;
    }
  }
  // butterfly merge across the 32 s-lanes of each u-group
#pragma unroll
  for (int off = 16; off; off >>= 1) {
#pragma unroll
    for (int q = 0; q < 5; q++) {
      float m2 = __shfl_xor(m[q], off, 64);
      float l2 = __shfl_xor(l[q], off, 64);
      float mn = fmaxf(m[q], m2);
      l[q] = l[q]*__expf(m[q]-mn) + l2*__expf(m2-mn);
      m[q] = mn;
    }
  }
  if (j == 0) {
#pragma unroll
    for (int q = 0; q < 5; q++) {
      int u = ig*5 + q;
      long p = ((long)(b*NH+h)*UU + u) * 2;
      stats[p] = m[q]; stats[p+1] = l[q];
    }
  }
}

// ---------------- normalize attn (in place) + PV -> out_head --------------
// block = (h, b); 256 threads: e = t%64, g = t/64 -> 10 u's each.
template<bool KV16>
__global__ __launch_bounds__(256, 2)
void attn_pv(float* __restrict__ attn, const void* __restrict__ Vkv,
             const float* __restrict__ stats, float* __restrict__ oh)
{
  const int h = blockIdx.x, b = blockIdx.y;
  __shared__ float Vs[64][68];
  __shared__ float As[UU][68];
  __shared__ float sM[UU], sLi[UU];
  const int t = threadIdx.x;
  const int e = t & 63, g = t >> 6;
  if (t < UU) {
    long p = ((long)(b*NH+h)*UU + t) * 2;
    sM[t]  = stats[p];
    sLi[t] = 1.f / stats[p+1];
  }
  float acc[10];
#pragma unroll
  for (int k = 0; k < 10; k++) acc[k] = 0.f;

  for (int s0 = 0; s0 < SSQ; s0 += 64) {
    __syncthreads();
    for (int idx = t; idx < 512; idx += 256) {
      int sl = idx >> 3, c8 = (idx & 7) * 8;
      float f[8];
      load8<KV16>(Vkv, (long)(b*SSQ + s0 + sl)*DM + h*HE + c8, f);
#pragma unroll
      for (int z = 0; z < 8; z++) Vs[sl][c8+z] = f[z];
    }
    for (int idx = t; idx < UU*64; idx += 256) {
      int u = idx >> 6, sl = idx & 63;
      long p = ((long)(b*NH+h)*UU + u)*SSQ + s0 + sl;
      float a = __expf(attn[p] - sM[u]) * sLi[u];
      attn[p] = a;
      As[u][sl] = a;
    }
    __syncthreads();
#pragma unroll
    for (int sl = 0; sl < 64; sl += 4) {
      float v0 = Vs[sl+0][e], v1 = Vs[sl+1][e], v2 = Vs[sl+2][e], v3 = Vs[sl+3][e];
#pragma unroll
      for (int k = 0; k < 10; k++) {
        float4 a4 = *(const float4*)&As[g*10+k][sl];
        acc[k] = fmaf(a4.x, v0, acc[k]);
        acc[k] = fmaf(a4.y, v1, acc[k]);
        acc[k] = fmaf(a4.z, v2, acc[k]);
        acc[k] = fmaf(a4.w, v3, acc[k]);
      }
    }
  }
#pragma unroll
  for (int k = 0; k < 10; k++) {
    int u = g*10 + k;
    oh[(long)(b*UU+u)*DM + h*HE + e] = acc[k];
  }
}

extern "C" void kernel_launch(void* const* d_in, const int* in_sizes, int n_in,
                              void* d_out, int out_size, void* d_ws, size_t ws_size,
                              hipStream_t stream)
{
  const float* queries = (const float*)d_in[0];
  const float* keys    = (const float*)d_in[1];
  const float* values  = (const float*)d_in[2];
  const float* Wq = (const float*)d_in[3];
  const float* bq = (const float*)d_in[4];
  const float* Wk = (const float*)d_in[5];
  const float* bk = (const float*)d_in[6];
  const float* Wv = (const float*)d_in[7];
  const float* bv = (const float*)d_in[8];
  const float* Wo = (const float*)d_in[9];
  const float* bo = (const float*)d_in[10];
  const int* sidx = (const int*)d_in[11];

  float* out_main = (float*)d_out;
  float* attn     = out_main + (long)NB*UU*DM;

  const long kvElems   = (long)NB*SSQ*DM;          // 33,554,432
  const long smallF    = (long)2*NB*UU*DM + (long)NB*NH*UU*2;  // Qs + OH + stats
  const bool kv32 = ws_size >= (size_t)(kvElems*8 + smallF*4 + 256);

  char* ws = (char*)d_ws;
  size_t kvBytes = kv32 ? (size_t)kvElems*4 : (size_t)kvElems*2;
  void*  Kbuf = (void*)ws;
  void*  Vbuf = (void*)(ws + kvBytes);
  float* Qsb  = (float*)(ws + 2*kvBytes);
  float* OH   = Qsb + (long)NB*UU*DM;
  float* ST   = OH  + (long)NB*UU*DM;

  dim3 blk(256);
  dim3 gkv(NB*SSQ/128, DM/128);         // (256, 8)
  dim3 gq((NB*UU + 127)/128, DM/128);   // (3, 8)
  dim3 gat(NH, NB);                     // (16, 8)

  if (kv32) {
    gemm_xwt<false,false><<<gkv,blk,0,stream>>>(keys,   Wk, bk, Kbuf, NB*SSQ, nullptr);
    gemm_xwt<false,false><<<gkv,blk,0,stream>>>(values, Wv, bv, Vbuf, NB*SSQ, nullptr);
  } else {
    gemm_xwt<false,true ><<<gkv,blk,0,stream>>>(keys,   Wk, bk, Kbuf, NB*SSQ, nullptr);
    gemm_xwt<false,true ><<<gkv,blk,0,stream>>>(values, Wv, bv, Vbuf, NB*SSQ, nullptr);
  }
  gemm_xwt<true,false><<<gq,blk,0,stream>>>(queries, Wq, bq, Qsb, NB*UU, sidx);

  if (kv32) {
    attn_scores<false><<<gat,blk,0,stream>>>(Qsb, Kbuf, attn, ST);
    attn_pv<false>    <<<gat,blk,0,stream>>>(attn, Vbuf, ST, OH);
  } else {
    attn_scores<true> <<<gat,blk,0,stream>>>(Qsb, Kbuf, attn, ST);
    attn_pv<true>     <<<gat,blk,0,stream>>>(attn, Vbuf, ST, OH);
  }
  gemm_xwt<false,false><<<gq,blk,0,stream>>>(OH, Wo, bo, out_main, NB*UU, nullptr);
}

// Round 2
// 960.232 us; speedup vs baseline: 3.0265x; 3.0265x over previous
//
#include <hip/hip_runtime.h>
#include <stdint.h>

#define DM  1024
#define NB  8
#define LQ  4096
#define SSQ 4096
#define NH  16
#define HE  64
#define UU  40
#define NS  8
#define SPL (SSQ/NS)

using u16 = unsigned short;
using u32 = unsigned int;

typedef __bf16 bf16x8 __attribute__((ext_vector_type(8)));
typedef float  f32x4  __attribute__((ext_vector_type(4)));

#define AS1 __attribute__((address_space(1)))
#define AS3 __attribute__((address_space(3)))

__device__ __forceinline__ void gld_lds16(const void* g, void* l) {
  __builtin_amdgcn_global_load_lds((const AS1 u32*)g, (AS3 u32*)l, 16, 0, 0);
}

__device__ __forceinline__ u16 f2bf(float x) {
  u32 u = __float_as_uint(x);
  u32 r = (u + 0x7fffu + ((u >> 16) & 1u)) >> 16;   // RNE
  return (u16)r;
}

// load 8 consecutive elements (fp32 or bf16 storage) into float[8]
template<bool KV16>
__device__ __forceinline__ void load8(const void* base, long off, float* f) {
  if (KV16) {
    uint4 raw = *(const uint4*)((const u16*)base + off);
    u32 w[4] = {raw.x, raw.y, raw.z, raw.w};
#pragma unroll
    for (int z = 0; z < 4; z++) {
      f[2*z]   = __uint_as_float(w[z] << 16);
      f[2*z+1] = __uint_as_float(w[z] & 0xffff0000u);
    }
  } else {
    const float* p = (const float*)base + off;
    float4 a = *(const float4*)p;
    float4 b = *(const float4*)(p + 4);
    f[0]=a.x; f[1]=a.y; f[2]=a.z; f[3]=a.w;
    f[4]=b.x; f[5]=b.y; f[6]=b.z; f[7]=b.w;
  }
}

// ---------------- fp32 -> bf16 convert ------------------------------------
__global__ __launch_bounds__(256)
void conv_bf16(const float* __restrict__ src, u16* __restrict__ dst, long n) {
  long i = ((long)blockIdx.x * 256 + threadIdx.x) * 8;
  if (i >= n) return;
  float4 a = *(const float4*)(src + i);
  float4 b = *(const float4*)(src + i + 4);
  union { u16 h[8]; uint4 v; } pk;
  pk.h[0]=f2bf(a.x); pk.h[1]=f2bf(a.y); pk.h[2]=f2bf(a.z); pk.h[3]=f2bf(a.w);
  pk.h[4]=f2bf(b.x); pk.h[5]=f2bf(b.y); pk.h[6]=f2bf(b.z); pk.h[7]=f2bf(b.w);
  *(uint4*)(dst + i) = pk.v;
}

// gather sampled query rows -> contiguous [NB*UU][DM] bf16
__global__ __launch_bounds__(128)
void gather_q_bf16(const float* __restrict__ q, const int* __restrict__ sidx,
                   u16* __restrict__ dst) {
  int r = blockIdx.x;                  // 0..NB*UU-1
  int b = r / UU, u = r - b*UU;
  long srow = ((long)b*LQ + sidx[u]) * DM;
  int c = threadIdx.x * 8;
  float4 a = *(const float4*)(q + srow + c);
  float4 bb = *(const float4*)(q + srow + c + 4);
  union { u16 h[8]; uint4 v; } pk;
  pk.h[0]=f2bf(a.x); pk.h[1]=f2bf(a.y); pk.h[2]=f2bf(a.z); pk.h[3]=f2bf(a.w);
  pk.h[4]=f2bf(bb.x); pk.h[5]=f2bf(bb.y); pk.h[6]=f2bf(bb.z); pk.h[7]=f2bf(bb.w);
  *(uint4*)(dst + (long)r*DM + c) = pk.v;
}

// ---------------- bf16 MFMA GEMM: C[r,o] = sum_k X[r,k]*W[o,k] + bias[o] --
// 128x128 tile, BK=32, 256 threads (4 waves, each 64x64), 16x16x32 mfma.
// LDS rows padded to 40 u16 (80 B) for bank spread; staged via global_load_lds.
template<bool OUT_BF16>
__global__ __launch_bounds__(256)
void gemm_mfma(const u16* __restrict__ Xb, const u16* __restrict__ Wb,
               const float* __restrict__ bias, void* __restrict__ outp, int R)
{
  __shared__ u16 As[128*40];     // 10240 B
  __shared__ u16 Bs[128*40];
  const int t = threadIdx.x;
  const int l = t & 63;
  const int w = t >> 6;
  const int r0 = blockIdx.x * 128;
  const int o0 = blockIdx.y * 128;

  // staging: 1280 16-B chunks per K-step (A:640, B:640 -- 5 per row, chunk 4 = pad)
  const u16* gsrc[5];
  char* ldst[5];
#pragma unroll
  for (int i = 0; i < 5; i++) {
    int c  = i*256 + t;           // per-thread chunk id
    int cb = i*256 + w*64;        // wave-uniform chunk base (640 % 64 == 0 -> same side)
    bool a = (cb < 640);
    int cc2 = a ? c : (c - 640);
    int row = cc2 / 5, col = cc2 % 5; if (col > 3) col = 0;  // pad chunk loads dup data
    if (a) {
      int rr = r0 + row; if (rr > R-1) rr = R-1;
      gsrc[i] = Xb + (long)rr * DM + col*8;
      ldst[i] = (char*)As + cb*16;
    } else {
      gsrc[i] = Wb + (long)(o0 + row) * DM + col*8;
      ldst[i] = (char*)Bs + (cb - 640)*16;
    }
  }

  f32x4 acc[4][4];
  const f32x4 z4 = {0.f, 0.f, 0.f, 0.f};
#pragma unroll
  for (int mt = 0; mt < 4; mt++)
#pragma unroll
    for (int nt = 0; nt < 4; nt++) acc[mt][nt] = z4;

  const int rw = (w >> 1) * 64;
  const int cw = (w & 1) * 64;
  const int fr = l & 15;
  const int fk = (l >> 4) * 8;

  for (int k0 = 0; k0 < DM; k0 += 32) {
    __syncthreads();
#pragma unroll
    for (int i = 0; i < 5; i++)
      gld_lds16(gsrc[i] + k0, ldst[i]);
    __syncthreads();

    bf16x8 af[4], bf[4];
#pragma unroll
    for (int mt = 0; mt < 4; mt++)
      af[mt] = *(const bf16x8*)&As[(rw + mt*16 + fr)*40 + fk];
#pragma unroll
    for (int nt = 0; nt < 4; nt++)
      bf[nt] = *(const bf16x8*)&Bs[(cw + nt*16 + fr)*40 + fk];
#pragma unroll
    for (int mt = 0; mt < 4; mt++)
#pragma unroll
      for (int nt = 0; nt < 4; nt++)
        acc[mt][nt] = __builtin_amdgcn_mfma_f32_16x16x32_bf16(af[mt], bf[nt], acc[mt][nt], 0, 0, 0);
  }

  // epilogue: D elem (reg i) = C[row=(l>>4)*4+i][col=l&15] within each 16x16 tile
  const int colBase = o0 + cw + (l & 15);
  const int rowBase = r0 + rw + ((l >> 4) << 2);
#pragma unroll
  for (int nt = 0; nt < 4; nt++) {
    float bv = bias[colBase + nt*16];
#pragma unroll
    for (int mt = 0; mt < 4; mt++) {
#pragma unroll
      for (int i2 = 0; i2 < 4; i2++) {
        int r = rowBase + mt*16 + i2;
        if (r < R) {
          float v = acc[mt][nt][i2] + bv;
          long o = (long)r*DM + colBase + nt*16;
          if (OUT_BF16) ((u16*)outp)[o] = f2bf(v);
          else          ((float*)outp)[o] = v;
        }
      }
    }
  }
}

// ---------------- scores + partial online softmax stats (s-split) --------
template<bool KV16>
__global__ __launch_bounds__(256, 2)
void attn_scores(const float* __restrict__ Qs, const void* __restrict__ Kkv,
                 float* __restrict__ attn, float* __restrict__ STp)
{
  const int h = blockIdx.x, b = blockIdx.y, z = blockIdx.z;
  __shared__ float Qss[UU][HE];
  __shared__ float Ks[64][68];
  const int t  = threadIdx.x;
  const int j  = t & 31, ig = t >> 5;

  for (int idx = t; idx < UU*HE; idx += 256) {
    int u = idx >> 6, e = idx & 63;
    Qss[u][e] = Qs[(long)(b*UU+u)*DM + h*HE + e];
  }
  float m[5], l[5];
#pragma unroll
  for (int q = 0; q < 5; q++) { m[q] = -1e30f; l[q] = 0.f; }

  for (int s0 = z*SPL; s0 < (z+1)*SPL; s0 += 64) {
    __syncthreads();
    for (int idx = t; idx < 512; idx += 256) {
      int sl = idx >> 3, c8 = (idx & 7) * 8;
      float f[8];
      load8<KV16>(Kkv, (long)(b*SSQ + s0 + sl)*DM + h*HE + c8, f);
#pragma unroll
      for (int zz = 0; zz < 8; zz++) Ks[sl][c8+zz] = f[zz];
    }
    __syncthreads();

    float acc0[5] = {0,0,0,0,0}, acc1[5] = {0,0,0,0,0};
#pragma unroll
    for (int e4 = 0; e4 < 64; e4 += 4) {
      float4 k0 = *(const float4*)&Ks[j][e4];
      float4 k1 = *(const float4*)&Ks[j+32][e4];
#pragma unroll
      for (int q = 0; q < 5; q++) {
        float4 qv = *(const float4*)&Qss[ig*5+q][e4];
        acc0[q] += qv.x*k0.x + qv.y*k0.y + qv.z*k0.z + qv.w*k0.w;
        acc1[q] += qv.x*k1.x + qv.y*k1.y + qv.z*k1.z + qv.w*k1.w;
      }
    }
    const float scale = 0.03125f;  // 1024^-0.5
#pragma unroll
    for (int q = 0; q < 5; q++) {
      int u = ig*5 + q;
      long row = ((long)(b*NH + h)*UU + u) * SSQ;
      float x0 = acc0[q]*scale, x1 = acc1[q]*scale;
      attn[row + s0 + j]      = x0;
      attn[row + s0 + 32 + j] = x1;
      float mn = fmaxf(m[q], fmaxf(x0, x1));
      l[q] = l[q]*__expf(m[q]-mn) + __expf(x0-mn) + __expf(x1-mn);
      m[q] = mn;
    }
  }
#pragma unroll
  for (int off = 16; off; off >>= 1) {
#pragma unroll
    for (int q = 0; q < 5; q++) {
      float m2 = __shfl_xor(m[q], off, 64);
      float l2 = __shfl_xor(l[q], off, 64);
      float mn = fmaxf(m[q], m2);
      l[q] = l[q]*__expf(m[q]-mn) + l2*__expf(m2-mn);
      m[q] = mn;
    }
  }
  if (j == 0) {
#pragma unroll
    for (int q = 0; q < 5; q++) {
      int u = ig*5 + q;
      long p = (((long)(b*NH+h)*UU + u)*NS + z) * 2;
      STp[p] = m[q]; STp[p+1] = l[q];
    }
  }
}

// ---------------- merge per-split (m,l) -> global (M,L) -------------------
__global__ __launch_bounds__(256)
void merge_stats(const float* __restrict__ STp, float* __restrict__ ST) {
  int idx = blockIdx.x*256 + threadIdx.x;
  if (idx >= NB*NH*UU) return;
  float M = -1e30f;
#pragma unroll
  for (int z = 0; z < NS; z++) M = fmaxf(M, STp[((long)idx*NS+z)*2]);
  float L = 0.f;
#pragma unroll
  for (int z = 0; z < NS; z++)
    L += STp[((long)idx*NS+z)*2+1] * __expf(STp[((long)idx*NS+z)*2] - M);
  ST[idx*2] = M; ST[idx*2+1] = L;
}

// ---------------- normalize attn (in place) + partial PV ------------------
template<bool KV16>
__global__ __launch_bounds__(256, 2)
void attn_pv(float* __restrict__ attn, const void* __restrict__ Vkv,
             const float* __restrict__ ST, float* __restrict__ ohp)
{
  const int h = blockIdx.x, b = blockIdx.y, z = blockIdx.z;
  __shared__ float Vs[64][68];
  __shared__ float As2[UU][68];
  __shared__ float sM[UU], sLi[UU];
  const int t = threadIdx.x;
  const int e = t & 63, g = t >> 6;
  if (t < UU) {
    long p = ((long)(b*NH+h)*UU + t) * 2;
    sM[t]  = ST[p];
    sLi[t] = 1.f / ST[p+1];
  }
  float acc[10];
#pragma unroll
  for (int k = 0; k < 10; k++) acc[k] = 0.f;

  for (int s0 = z*SPL; s0 < (z+1)*SPL; s0 += 64) {
    __syncthreads();
    for (int idx = t; idx < 512; idx += 256) {
      int sl = idx >> 3, c8 = (idx & 7) * 8;
      float f[8];
      load8<KV16>(Vkv, (long)(b*SSQ + s0 + sl)*DM + h*HE + c8, f);
#pragma unroll
      for (int zz = 0; zz < 8; zz++) Vs[sl][c8+zz] = f[zz];
    }
    for (int idx = t; idx < UU*64; idx += 256) {
      int u = idx >> 6, sl = idx & 63;
      long p = ((long)(b*NH+h)*UU + u)*SSQ + s0 + sl;
      float a = __expf(attn[p] - sM[u]) * sLi[u];
      attn[p] = a;
      As2[u][sl] = a;
    }
    __syncthreads();
#pragma unroll
    for (int sl = 0; sl < 64; sl += 4) {
      float v0 = Vs[sl+0][e], v1 = Vs[sl+1][e], v2 = Vs[sl+2][e], v3 = Vs[sl+3][e];
#pragma unroll
      for (int k = 0; k < 10; k++) {
        float4 a4 = *(const float4*)&As2[g*10+k][sl];
        acc[k] = fmaf(a4.x, v0, acc[k]);
        acc[k] = fmaf(a4.y, v1, acc[k]);
        acc[k] = fmaf(a4.z, v2, acc[k]);
        acc[k] = fmaf(a4.w, v3, acc[k]);
      }
    }
  }
#pragma unroll
  for (int k = 0; k < 10; k++) {
    int u = g*10 + k;
    ohp[((long)z*NB*UU + b*UU + u)*DM + h*HE + e] = acc[k];
  }
}

// ---------------- reduce PV partials -> bf16 OH ---------------------------
__global__ __launch_bounds__(256)
void reduce_oh(const float* __restrict__ ohp, u16* __restrict__ ohb) {
  long i = (long)blockIdx.x*256 + threadIdx.x;
  const long n = (long)NB*UU*DM;
  if (i >= n) return;
  float s = 0.f;
#pragma unroll
  for (int z = 0; z < NS; z++) s += ohp[(long)z*n + i];
  ohb[i] = f2bf(s);
}

extern "C" void kernel_launch(void* const* d_in, const int* in_sizes, int n_in,
                              void* d_out, int out_size, void* d_ws, size_t ws_size,
                              hipStream_t stream)
{
  const float* queries = (const float*)d_in[0];
  const float* keys    = (const float*)d_in[1];
  const float* values  = (const float*)d_in[2];
  const float* Wq = (const float*)d_in[3];
  const float* bq = (const float*)d_in[4];
  const float* Wk = (const float*)d_in[5];
  const float* bk = (const float*)d_in[6];
  const float* Wv = (const float*)d_in[7];
  const float* bv = (const float*)d_in[8];
  const float* Wo = (const float*)d_in[9];
  const float* bo = (const float*)d_in[10];
  const int* sidx = (const int*)d_in[11];

  float* out_main = (float*)d_out;
  float* attn     = out_main + (long)NB*UU*DM;

  const long kvE   = (long)NB*SSQ*DM;       // 33,554,432
  const size_t stageB = (size_t)kvE*2;      // bf16 staging for keys/values
  const size_t wB     = (size_t)DM*DM*2;    // one bf16 weight
  const size_t smallB = (size_t)(NB*UU*DM)*(2+4+2)      // Qgb + Qsb + OHb
                      + (size_t)NS*NB*UU*DM*4           // ohp
                      + (size_t)NB*NH*UU*NS*2*4         // STp
                      + (size_t)NB*NH*UU*2*4 + 4096;    // ST
  const bool kv32 = ws_size >= stageB + (size_t)kvE*8 + 4*wB + smallB;

  char* ws = (char*)d_ws;
  u16*  Xst  = (u16*)ws;                         ws += stageB;
  size_t kvBytes = kv32 ? (size_t)kvE*4 : (size_t)kvE*2;
  void* Kbuf = (void*)ws;                        ws += kvBytes;
  void* Vbuf = (void*)ws;                        ws += kvBytes;
  u16*  Wkb = (u16*)ws;                          ws += wB;
  u16*  Wvb = (u16*)ws;                          ws += wB;
  u16*  Wqb = (u16*)ws;                          ws += wB;
  u16*  Wob = (u16*)ws;                          ws += wB;
  u16*  Qgb = (u16*)ws;                          ws += (size_t)NB*UU*DM*2;
  float* Qsb = (float*)ws;                       ws += (size_t)NB*UU*DM*4;
  u16*  OHb = (u16*)ws;                          ws += (size_t)NB*UU*DM*2;
  float* ohp = (float*)ws;                       ws += (size_t)NS*NB*UU*DM*4;
  float* STp = (float*)ws;                       ws += (size_t)NB*NH*UU*NS*2*4;
  float* ST  = (float*)ws;

  dim3 blk(256);
  const long wN = (long)DM*DM;
  dim3 gconvW((wN/8 + 255)/256);
  dim3 gconvX((kvE/8 + 255)/256);
  dim3 gkv(NB*SSQ/128, DM/128);     // (256, 8)
  dim3 gq((NB*UU + 127)/128, DM/128);
  dim3 gat(NH, NB, NS);

  conv_bf16<<<gconvW, blk, 0, stream>>>(Wk, Wkb, wN);
  conv_bf16<<<gconvW, blk, 0, stream>>>(Wv, Wvb, wN);
  conv_bf16<<<gconvW, blk, 0, stream>>>(Wq, Wqb, wN);
  conv_bf16<<<gconvW, blk, 0, stream>>>(Wo, Wob, wN);
  gather_q_bf16<<<NB*UU, 128, 0, stream>>>(queries, sidx, Qgb);

  conv_bf16<<<gconvX, blk, 0, stream>>>(keys, Xst, kvE);
  if (kv32) gemm_mfma<false><<<gkv, blk, 0, stream>>>(Xst, Wkb, bk, Kbuf, NB*SSQ);
  else      gemm_mfma<true ><<<gkv, blk, 0, stream>>>(Xst, Wkb, bk, Kbuf, NB*SSQ);
  conv_bf16<<<gconvX, blk, 0, stream>>>(values, Xst, kvE);
  if (kv32) gemm_mfma<false><<<gkv, blk, 0, stream>>>(Xst, Wvb, bv, Vbuf, NB*SSQ);
  else      gemm_mfma<true ><<<gkv, blk, 0, stream>>>(Xst, Wvb, bv, Vbuf, NB*SSQ);

  gemm_mfma<false><<<gq, blk, 0, stream>>>(Qgb, Wqb, bq, Qsb, NB*UU);

  if (kv32) {
    attn_scores<false><<<gat, blk, 0, stream>>>(Qsb, Kbuf, attn, STp);
    merge_stats<<<(NB*NH*UU + 255)/256, blk, 0, stream>>>(STp, ST);
    attn_pv<false><<<gat, blk, 0, stream>>>(attn, Vbuf, ST, ohp);
  } else {
    attn_scores<true ><<<gat, blk, 0, stream>>>(Qsb, Kbuf, attn, STp);
    merge_stats<<<(NB*NH*UU + 255)/256, blk, 0, stream>>>(STp, ST);
    attn_pv<true ><<<gat, blk, 0, stream>>>(attn, Vbuf, ST, ohp);
  }
  reduce_oh<<<((long)NB*UU*DM + 255)/256, blk, 0, stream>>>(ohp, OHb);
  gemm_mfma<false><<<gq, blk, 0, stream>>>(OHb, Wob, bo, out_main, NB*UU);
}